// Round 1
// baseline (138.195 us; speedup 1.0000x reference)
//
#include <hip/hip_runtime.h>
#include <hip/hip_bf16.h>

typedef float  f32x4_v  __attribute__((ext_vector_type(4)));
typedef __bf16 bf16x8_v __attribute__((ext_vector_type(8)));
typedef __bf16 bf16x4_v __attribute__((ext_vector_type(4)));

// Workspace layout (in __bf16 elements):
//   Q  [64][1024][128]          @ 0
//   K  [64][1024][128]          @ 8388608
//   V  [64][128][1024]  (c,p!)  @ 16777216
//   O  [64][1024][128]          @ 25165824
//   Wp [4][128][128]            @ 33554432   (w_out permuted: c2 = c*4+head)
// total = 33620 KB *2B = 67.24 MB
#define WS_Q  0
#define WS_K  8388608
#define WS_V  16777216
#define WS_O  25165824
#define WS_WP 33554432

__device__ __forceinline__ int aswz(int p) { return ((p & 7) ^ ((p >> 3) & 7)) << 4; }

// ---------------- kernel 0: permute w_out ----------------
// w_perm[head*16384 + o*128 + c] = w_out[o*512 + c*4 + head]
__global__ __launch_bounds__(256) void k_permute(const float* __restrict__ w_out,
                                                 __bf16* __restrict__ w_perm) {
    int idx  = blockIdx.x * 256 + threadIdx.x;   // 65536 total
    int head = idx >> 14;
    int o    = (idx >> 7) & 127;
    int c    = idx & 127;
    w_perm[idx] = (__bf16)w_out[o * 512 + c * 4 + head];
}

// ---------------- kernel 1: QKV GEMM ----------------
// M=16384 (b*1024+p), N=1536 (o), K=128 (c). 128x128 tile, 4 waves (2x2 of 64x64).
__global__ __launch_bounds__(256) void k_qkv(const float* __restrict__ x,
                                             const float* __restrict__ w_qkv,
                                             const float* __restrict__ b_qkv,
                                             __bf16* __restrict__ q_ws,
                                             __bf16* __restrict__ k_ws,
                                             __bf16* __restrict__ v_ws) {
    __shared__ __bf16 Ash[128 * 128];   // swizzled [p][c]
    __shared__ __bf16 Bsh[128 * 128];   // swizzled [o][c]
    const int tid = threadIdx.x;
    const int nt  = blockIdx.x;          // 0..11
    const int mt  = blockIdx.y;          // 0..127
    const int gm0 = mt * 128;
    const int b   = gm0 >> 10;
    const int p0  = gm0 & 1023;
    const int o0  = nt * 128;

    char* Ab = reinterpret_cast<char*>(Ash);
    char* Bb = reinterpret_cast<char*>(Bsh);

    // stage A: x[b][c][p0+i] -> Ash[p][c] (transpose, swizzled scalar writes)
    for (int it = 0; it < 16; ++it) {
        int idx = tid + it * 256;            // 0..4095
        int c   = idx >> 5;                  // 0..127
        int i4  = (idx & 31) << 2;           // p_local base
        float4 v = *reinterpret_cast<const float4*>(x + b * 131072 + c * 1024 + p0 + i4);
        float vv[4] = {v.x, v.y, v.z, v.w};
#pragma unroll
        for (int j = 0; j < 4; ++j) {
            int p = i4 + j;
            int byte = ((p << 8) | (c << 1)) ^ aswz(p);
            *reinterpret_cast<__bf16*>(Ab + byte) = (__bf16)vv[j];
        }
    }
    // stage B: w_qkv[o0+o][c] -> Bsh[o][c] (row-major already, swizzled 8B writes)
    for (int it = 0; it < 16; ++it) {
        int idx = tid + it * 256;
        int o   = idx >> 5;
        int c4  = (idx & 31) << 2;
        float4 v = *reinterpret_cast<const float4*>(w_qkv + (o0 + o) * 128 + c4);
        bf16x4_v h;
        h[0] = (__bf16)v.x; h[1] = (__bf16)v.y; h[2] = (__bf16)v.z; h[3] = (__bf16)v.w;
        int byte = ((o << 8) | (c4 << 1)) ^ aswz(o);
        *reinterpret_cast<bf16x4_v*>(Bb + byte) = h;
    }
    __syncthreads();

    const int lane = tid & 63;
    const int wv   = tid >> 6;
    const int wm   = (wv >> 1) * 64;
    const int wn   = (wv & 1) * 64;
    const int lr   = lane & 15;
    const int lg   = lane >> 4;

    f32x4_v acc[4][4] = {};
#pragma unroll
    for (int ks = 0; ks < 4; ++ks) {
        bf16x8_v af[4], bfr[4];
#pragma unroll
        for (int mi = 0; mi < 4; ++mi) {
            int row  = wm + mi * 16 + lr;
            int byte = ((row << 8) | (ks << 6) | (lg << 4)) ^ aswz(row);
            af[mi] = *reinterpret_cast<const bf16x8_v*>(Ab + byte);
        }
#pragma unroll
        for (int ni = 0; ni < 4; ++ni) {
            int row  = wn + ni * 16 + lr;
            int byte = ((row << 8) | (ks << 6) | (lg << 4)) ^ aswz(row);
            bfr[ni] = *reinterpret_cast<const bf16x8_v*>(Bb + byte);
        }
#pragma unroll
        for (int mi = 0; mi < 4; ++mi)
#pragma unroll
            for (int ni = 0; ni < 4; ++ni)
                acc[mi][ni] = __builtin_amdgcn_mfma_f32_16x16x32_bf16(af[mi], bfr[ni], acc[mi][ni], 0, 0, 0);
    }

    // epilogue: split o -> (head, type, ch); Q scaled by 1/sqrt(128); V stored [bh][ch][p]
#pragma unroll
    for (int ni = 0; ni < 4; ++ni) {
        int o    = o0 + wn + ni * 16 + lr;
        int head = o / 384;
        int rem  = o - head * 384;
        int type = rem >> 7;
        int ch   = rem & 127;
        float bias = b_qkv[o];
        int bh   = (b << 2) + head;
#pragma unroll
        for (int mi = 0; mi < 4; ++mi) {
            int prow = p0 + wm + mi * 16 + lg * 4;
            f32x4_v a = acc[mi][ni];
            if (type == 0) {
#pragma unroll
                for (int r = 0; r < 4; ++r)
                    q_ws[bh * 131072 + (prow + r) * 128 + ch] =
                        (__bf16)((a[r] + bias) * 0.08838834764831845f);
            } else if (type == 1) {
#pragma unroll
                for (int r = 0; r < 4; ++r)
                    k_ws[bh * 131072 + (prow + r) * 128 + ch] = (__bf16)(a[r] + bias);
            } else {
                bf16x4_v hv;
#pragma unroll
                for (int r = 0; r < 4; ++r) hv[r] = (__bf16)(a[r] + bias);
                *reinterpret_cast<bf16x4_v*>(&v_ws[bh * 131072 + ch * 1024 + prow]) = hv;
            }
        }
    }
}

// ---------------- kernel 2: flash attention ----------------
// grid (16 qtiles, 64 bh), 4 waves; wave owns 16 q rows; KV tiles of 64.
__global__ __launch_bounds__(256) void k_attn(const __bf16* __restrict__ q_ws,
                                              const __bf16* __restrict__ k_ws,
                                              const __bf16* __restrict__ v_ws,
                                              __bf16* __restrict__ o_ws) {
    __shared__ __bf16 Kl[64 * 136];      // [kv][d] pad 136
    __shared__ __bf16 Vl[128 * 72];      // [d][kv] pad 72
    __shared__ __bf16 Pl[4 * 16 * 72];   // per-wave [q][kv] pad 72
    const int tid  = threadIdx.x;
    const int lane = tid & 63, wv = tid >> 6;
    const int lr   = lane & 15, lg = lane >> 4;
    const int qt   = blockIdx.x;         // 0..15
    const int bh   = blockIdx.y;         // 0..63
    const int base = bh * 131072;
    const int q0   = qt * 64 + wv * 16;

    bf16x8_v aq[4];
#pragma unroll
    for (int ks = 0; ks < 4; ++ks)
        aq[ks] = *reinterpret_cast<const bf16x8_v*>(&q_ws[base + (q0 + lr) * 128 + ks * 32 + lg * 8]);

    f32x4_v of[8] = {};
    float m[4], l[4];
#pragma unroll
    for (int r = 0; r < 4; ++r) { m[r] = -1e30f; l[r] = 0.f; }

    for (int kt = 0; kt < 16; ++kt) {
        const int kv0 = kt * 64;
        __syncthreads();
#pragma unroll
        for (int it = 0; it < 4; ++it) {        // K: [kv][d]
            int idx = tid + it * 256;
            int kv = idx >> 4, d8 = (idx & 15) * 8;
            *reinterpret_cast<bf16x8_v*>(&Kl[kv * 136 + d8]) =
                *reinterpret_cast<const bf16x8_v*>(&k_ws[base + (kv0 + kv) * 128 + d8]);
        }
#pragma unroll
        for (int it = 0; it < 4; ++it) {        // V (pre-transposed): [d][kv]
            int idx = tid + it * 256;
            int d = idx >> 3, k8 = (idx & 7) * 8;
            *reinterpret_cast<bf16x8_v*>(&Vl[d * 72 + k8]) =
                *reinterpret_cast<const bf16x8_v*>(&v_ws[base + d * 1024 + kv0 + k8]);
        }
        __syncthreads();

        // S = Q K^T (scale folded into Q)
        f32x4_v s[4] = {};
#pragma unroll
        for (int ks = 0; ks < 4; ++ks)
#pragma unroll
            for (int ni = 0; ni < 4; ++ni) {
                bf16x8_v bk = *reinterpret_cast<const bf16x8_v*>(&Kl[(ni * 16 + lr) * 136 + ks * 32 + lg * 8]);
                s[ni] = __builtin_amdgcn_mfma_f32_16x16x32_bf16(aq[ks], bk, s[ni], 0, 0, 0);
            }

        // online softmax: row = lg*4+r, cols spread over lanes 0..15 of each group
        float fr[4];
#pragma unroll
        for (int r = 0; r < 4; ++r) {
            float v = fmaxf(fmaxf(s[0][r], s[1][r]), fmaxf(s[2][r], s[3][r]));
            v = fmaxf(v, __shfl_xor(v, 1));
            v = fmaxf(v, __shfl_xor(v, 2));
            v = fmaxf(v, __shfl_xor(v, 4));
            v = fmaxf(v, __shfl_xor(v, 8));
            float mn = fmaxf(m[r], v);
            fr[r] = __expf(m[r] - mn);
            m[r] = mn;
        }
        float rs[4] = {0.f, 0.f, 0.f, 0.f};
#pragma unroll
        for (int ni = 0; ni < 4; ++ni) {
#pragma unroll
            for (int r = 0; r < 4; ++r) {
                float e = __expf(s[ni][r] - m[r]);
                rs[r] += e;
                Pl[wv * 1152 + (lg * 4 + r) * 72 + ni * 16 + lr] = (__bf16)e;
            }
        }
#pragma unroll
        for (int r = 0; r < 4; ++r) {
            float v = rs[r];
            v += __shfl_xor(v, 1);
            v += __shfl_xor(v, 2);
            v += __shfl_xor(v, 4);
            v += __shfl_xor(v, 8);
            l[r] = l[r] * fr[r] + v;
        }
#pragma unroll
        for (int nf = 0; nf < 8; ++nf)
#pragma unroll
            for (int r = 0; r < 4; ++r) of[nf][r] *= fr[r];

        asm volatile("s_waitcnt lgkmcnt(0)" ::: "memory");
        __builtin_amdgcn_sched_barrier(0);

        // O += P V   (A=P 16x64, B=V 64x128)
#pragma unroll
        for (int ks2 = 0; ks2 < 2; ++ks2) {
            bf16x8_v ap = *reinterpret_cast<const bf16x8_v*>(&Pl[wv * 1152 + lr * 72 + ks2 * 32 + lg * 8]);
#pragma unroll
            for (int nf = 0; nf < 8; ++nf) {
                bf16x8_v bv = *reinterpret_cast<const bf16x8_v*>(&Vl[(nf * 16 + lr) * 72 + ks2 * 32 + lg * 8]);
                of[nf] = __builtin_amdgcn_mfma_f32_16x16x32_bf16(ap, bv, of[nf], 0, 0, 0);
            }
        }
    }

    // epilogue: O /= l, write [bh][p][d]
#pragma unroll
    for (int r = 0; r < 4; ++r) {
        float inv = 1.0f / l[r];
        int p = q0 + lg * 4 + r;
#pragma unroll
        for (int nf = 0; nf < 8; ++nf) {
            int d = nf * 16 + lr;
            o_ws[base + p * 128 + d] = (__bf16)(of[nf][r] * inv);
        }
    }
}

// ---------------- kernel 3: out-proj + bias + residual ----------------
// M=16384, K=512 (chunked as 4 heads of 128), N=128. BM=64, 4 waves of 16 rows.
__global__ __launch_bounds__(256) void k_out(const __bf16* __restrict__ o_ws,
                                             const __bf16* __restrict__ w_perm,
                                             const float* __restrict__ b_out,
                                             const float* __restrict__ x,
                                             float* __restrict__ out) {
    __shared__ __bf16 Al[64 * 136];
    __shared__ __bf16 Bl[128 * 136];
    const int tid  = threadIdx.x;
    const int lane = tid & 63, wv = tid >> 6;
    const int lr   = lane & 15, lg = lane >> 4;
    const int mt   = blockIdx.x;         // 0..255
    const int gp0  = mt * 64;
    const int b    = gp0 >> 10;
    const int p0   = gp0 & 1023;

    f32x4_v acc[8] = {};
    for (int kc = 0; kc < 4; ++kc) {     // kc == head (k' = head*128 + c)
        __syncthreads();
#pragma unroll
        for (int it = 0; it < 4; ++it) { // A: O_ws[b*4+kc][p0+r][c]
            int idx = tid + it * 256;
            int rr = idx >> 4, k8 = (idx & 15) * 8;
            *reinterpret_cast<bf16x8_v*>(&Al[rr * 136 + k8]) =
                *reinterpret_cast<const bf16x8_v*>(&o_ws[(b * 4 + kc) * 131072 + (p0 + rr) * 128 + k8]);
        }
#pragma unroll
        for (int it = 0; it < 8; ++it) { // B: w_perm[kc][o][c]
            int idx = tid + it * 256;
            int o = idx >> 4, k8 = (idx & 15) * 8;
            *reinterpret_cast<bf16x8_v*>(&Bl[o * 136 + k8]) =
                *reinterpret_cast<const bf16x8_v*>(&w_perm[kc * 16384 + o * 128 + k8]);
        }
        __syncthreads();
#pragma unroll
        for (int ks = 0; ks < 4; ++ks) {
            bf16x8_v af = *reinterpret_cast<const bf16x8_v*>(&Al[(wv * 16 + lr) * 136 + ks * 32 + lg * 8]);
#pragma unroll
            for (int ni = 0; ni < 8; ++ni) {
                bf16x8_v bf_ = *reinterpret_cast<const bf16x8_v*>(&Bl[(ni * 16 + lr) * 136 + ks * 32 + lg * 8]);
                acc[ni] = __builtin_amdgcn_mfma_f32_16x16x32_bf16(af, bf_, acc[ni], 0, 0, 0);
            }
        }
    }

    int prow = p0 + wv * 16 + lg * 4;
#pragma unroll
    for (int ni = 0; ni < 8; ++ni) {
        int o = ni * 16 + lr;
        float bias = b_out[o];
        float4 xr = *reinterpret_cast<const float4*>(&x[b * 131072 + o * 1024 + prow]);
        float4 res;
        res.x = acc[ni][0] + bias + xr.x;
        res.y = acc[ni][1] + bias + xr.y;
        res.z = acc[ni][2] + bias + xr.z;
        res.w = acc[ni][3] + bias + xr.w;
        *reinterpret_cast<float4*>(&out[b * 131072 + o * 1024 + prow]) = res;
    }
}

extern "C" void kernel_launch(void* const* d_in, const int* in_sizes, int n_in,
                              void* d_out, int out_size, void* d_ws, size_t ws_size,
                              hipStream_t stream) {
    const float* x     = (const float*)d_in[0];
    const float* w_qkv = (const float*)d_in[1];
    const float* b_qkv = (const float*)d_in[2];
    const float* w_out = (const float*)d_in[3];
    const float* b_out = (const float*)d_in[4];
    float* out = (float*)d_out;
    __bf16* ws = (__bf16*)d_ws;

    __bf16* q_ws   = ws + WS_Q;
    __bf16* k_ws   = ws + WS_K;
    __bf16* v_ws   = ws + WS_V;
    __bf16* o_ws   = ws + WS_O;
    __bf16* w_perm = ws + WS_WP;

    k_permute<<<256, 256, 0, stream>>>(w_out, w_perm);
    k_qkv<<<dim3(12, 128), 256, 0, stream>>>(x, w_qkv, b_qkv, q_ws, k_ws, v_ws);
    k_attn<<<dim3(16, 64), 256, 0, stream>>>(q_ws, k_ws, v_ws, o_ws);
    k_out<<<256, 256, 0, stream>>>(o_ws, w_perm, b_out, x, out);
}

// Round 2
// 92.827 us; speedup vs baseline: 1.4887x; 1.4887x over previous
//
#include <hip/hip_runtime.h>
#include <hip/hip_bf16.h>

typedef float  f32x4_v   __attribute__((ext_vector_type(4)));
typedef float  f32x16_v  __attribute__((ext_vector_type(16)));
typedef __bf16 bf16x8_v  __attribute__((ext_vector_type(8)));
typedef __bf16 bf16x4_v  __attribute__((ext_vector_type(4)));

// Workspace layout (in __bf16 elements):
//   Q  [64][1024][128]          @ 0          (pre-scaled by 1/sqrt(128)*log2(e))
//   K  [64][1024][128]          @ 8388608
//   V  [64][128][1024]  (c,p!)  @ 16777216
//   O  [64][1024][128]          @ 25165824
//   Wp [4][128][128]            @ 33554432
#define WS_Q  0
#define WS_K  8388608
#define WS_V  16777216
#define WS_O  25165824
#define WS_WP 33554432

__device__ __forceinline__ int aswz(int p) { return ((p & 7) ^ ((p >> 3) & 7)) << 4; }

__device__ __forceinline__ void gload16(const void* g, void* l) {
    __builtin_amdgcn_global_load_lds(
        (const __attribute__((address_space(1))) unsigned int*)g,
        (__attribute__((address_space(3))) unsigned int*)l, 16, 0, 0);
}

// ---------------- kernel 0: permute w_out ----------------
__global__ __launch_bounds__(256) void k_permute(const float* __restrict__ w_out,
                                                 __bf16* __restrict__ w_perm) {
    int idx  = blockIdx.x * 256 + threadIdx.x;
    int head = idx >> 14;
    int o    = (idx >> 7) & 127;
    int c    = idx & 127;
    w_perm[idx] = (__bf16)w_out[o * 512 + c * 4 + head];
}

// ---------------- kernel 1: QKV GEMM ----------------
__global__ __launch_bounds__(256) void k_qkv(const float* __restrict__ x,
                                             const float* __restrict__ w_qkv,
                                             const float* __restrict__ b_qkv,
                                             __bf16* __restrict__ q_ws,
                                             __bf16* __restrict__ k_ws,
                                             __bf16* __restrict__ v_ws) {
    __shared__ __bf16 Ash[128 * 128];
    __shared__ __bf16 Bsh[128 * 128];
    const int tid = threadIdx.x;
    const int nt  = blockIdx.x;
    const int mt  = blockIdx.y;
    const int gm0 = mt * 128;
    const int b   = gm0 >> 10;
    const int p0  = gm0 & 1023;
    const int o0  = nt * 128;

    char* Ab = reinterpret_cast<char*>(Ash);
    char* Bb = reinterpret_cast<char*>(Bsh);

    for (int it = 0; it < 16; ++it) {
        int idx = tid + it * 256;
        int c   = idx >> 5;
        int i4  = (idx & 31) << 2;
        float4 v = *reinterpret_cast<const float4*>(x + b * 131072 + c * 1024 + p0 + i4);
        float vv[4] = {v.x, v.y, v.z, v.w};
#pragma unroll
        for (int j = 0; j < 4; ++j) {
            int p = i4 + j;
            int byte = ((p << 8) | (c << 1)) ^ aswz(p);
            *reinterpret_cast<__bf16*>(Ab + byte) = (__bf16)vv[j];
        }
    }
    for (int it = 0; it < 16; ++it) {
        int idx = tid + it * 256;
        int o   = idx >> 5;
        int c4  = (idx & 31) << 2;
        float4 v = *reinterpret_cast<const float4*>(w_qkv + (o0 + o) * 128 + c4);
        bf16x4_v h;
        h[0] = (__bf16)v.x; h[1] = (__bf16)v.y; h[2] = (__bf16)v.z; h[3] = (__bf16)v.w;
        int byte = ((o << 8) | (c4 << 1)) ^ aswz(o);
        *reinterpret_cast<bf16x4_v*>(Bb + byte) = h;
    }
    __syncthreads();

    const int lane = tid & 63;
    const int wv   = tid >> 6;
    const int wm   = (wv >> 1) * 64;
    const int wn   = (wv & 1) * 64;
    const int lr   = lane & 15;
    const int lg   = lane >> 4;

    f32x4_v acc[4][4] = {};
#pragma unroll
    for (int ks = 0; ks < 4; ++ks) {
        bf16x8_v af[4], bfr[4];
#pragma unroll
        for (int mi = 0; mi < 4; ++mi) {
            int row  = wm + mi * 16 + lr;
            int byte = ((row << 8) | (ks << 6) | (lg << 4)) ^ aswz(row);
            af[mi] = *reinterpret_cast<const bf16x8_v*>(Ab + byte);
        }
#pragma unroll
        for (int ni = 0; ni < 4; ++ni) {
            int row  = wn + ni * 16 + lr;
            int byte = ((row << 8) | (ks << 6) | (lg << 4)) ^ aswz(row);
            bfr[ni] = *reinterpret_cast<const bf16x8_v*>(Bb + byte);
        }
#pragma unroll
        for (int mi = 0; mi < 4; ++mi)
#pragma unroll
            for (int ni = 0; ni < 4; ++ni)
                acc[mi][ni] = __builtin_amdgcn_mfma_f32_16x16x32_bf16(af[mi], bfr[ni], acc[mi][ni], 0, 0, 0);
    }

#pragma unroll
    for (int ni = 0; ni < 4; ++ni) {
        int o    = o0 + wn + ni * 16 + lr;
        int head = o / 384;
        int rem  = o - head * 384;
        int type = rem >> 7;
        int ch   = rem & 127;
        float bias = b_qkv[o];
        int bh   = (b << 2) + head;
#pragma unroll
        for (int mi = 0; mi < 4; ++mi) {
            int prow = p0 + wm + mi * 16 + lg * 4;
            f32x4_v a = acc[mi][ni];
            if (type == 0) {
#pragma unroll
                for (int r = 0; r < 4; ++r)
                    q_ws[bh * 131072 + (prow + r) * 128 + ch] =
                        (__bf16)((a[r] + bias) * 0.12751744f);   // 1/sqrt(128) * log2(e)
            } else if (type == 1) {
#pragma unroll
                for (int r = 0; r < 4; ++r)
                    k_ws[bh * 131072 + (prow + r) * 128 + ch] = (__bf16)(a[r] + bias);
            } else {
                bf16x4_v hv;
#pragma unroll
                for (int r = 0; r < 4; ++r) hv[r] = (__bf16)(a[r] + bias);
                *reinterpret_cast<bf16x4_v*>(&v_ws[bh * 131072 + ch * 1024 + prow]) = hv;
            }
        }
    }
}

// ---------------- kernel 2: flash attention (4 waves x 32 q, 32x32x16, swapped QK^T) ----------------
// grid: 512 blocks 1D, XCD-bijective decode; KVBLK=64, double-buffered LDS via global_load_lds.
__device__ __forceinline__ void stage_kv(const __bf16* kg, const __bf16* vg,
                                         __bf16* kl, __bf16* vl, int wv, int lane) {
    const int s16 = lane & 15, r4 = lane >> 4;
    const int s8  = lane & 7,  r8 = lane >> 3;
#pragma unroll
    for (int i = 0; i < 4; ++i) {     // K tile: 64 rows x 256B (rows of [p][d])
        int row = wv * 16 + i * 4 + r4;
        const char* src = (const char*)(kg + row * 128) + ((s16 ^ (row & 7)) << 4);
        char* dst = (char*)kl + (wv * 16 + i * 4) * 256;
        gload16(src, dst);
    }
#pragma unroll
    for (int i = 0; i < 4; ++i) {     // V^T tile: 128 rows x 128B (rows of [d][p])
        int row = wv * 32 + i * 8 + r8;
        const char* src = (const char*)(vg + row * 1024) + ((s8 ^ (row & 7)) << 4);
        char* dst = (char*)vl + (wv * 32 + i * 8) * 128;
        gload16(src, dst);
    }
}

__global__ __launch_bounds__(256, 2) void k_attn(const __bf16* __restrict__ q_ws,
                                                 const __bf16* __restrict__ k_ws,
                                                 const __bf16* __restrict__ v_ws,
                                                 __bf16* __restrict__ o_ws) {
    __shared__ __bf16 Kbuf[2][64 * 128];
    __shared__ __bf16 Vbuf[2][128 * 64];

    const int tid  = threadIdx.x;
    const int lane = tid & 63;
    const int wv   = tid >> 6;
    const int col  = lane & 31;       // q index in S-layout; d index in O-layout
    const int hi   = lane >> 5;

    // XCD-bijective: id = bh_hi + 8*(qt + 8*bh_lo); all 8 q-tiles of a bh share one XCD
    const int id   = blockIdx.x;
    const int bh   = (id & 7) * 8 + (id >> 6);
    const int qt   = (id >> 3) & 7;
    const int base = bh * 131072;
    const int q0w  = qt * 128 + wv * 32;

    // Q fragments in regs: B-operand rows, k = ks*16 + 8*hi + e
    bf16x8_v bq[8];
    const __bf16* qp = q_ws + base + (q0w + col) * 128 + hi * 8;
#pragma unroll
    for (int ks = 0; ks < 8; ++ks)
        bq[ks] = *reinterpret_cast<const bf16x8_v*>(qp + ks * 16);

    f32x16_v of[4] = {};
    float m = -1e30f, l = 0.f;

    stage_kv(k_ws + base, v_ws + base, &Kbuf[0][0], &Vbuf[0][0], wv, lane);

    for (int t = 0; t < 16; ++t) {
        const int cur = t & 1;
        if (t < 15) {
            stage_kv(k_ws + base + (t + 1) * 64 * 128, v_ws + base + (t + 1) * 64,
                     &Kbuf[cur ^ 1][0], &Vbuf[cur ^ 1][0], wv, lane);
            asm volatile("s_waitcnt vmcnt(8)" ::: "memory");   // cur tile's 8 loads done
        } else {
            asm volatile("s_waitcnt vmcnt(0)" ::: "memory");
        }
        __builtin_amdgcn_s_barrier();
        asm volatile("" ::: "memory");
        __builtin_amdgcn_sched_barrier(0);

        const char* Kl = (const char*)&Kbuf[cur][0];
        const char* Vl = (const char*)&Vbuf[cur][0];

        // ---- S^T = K * Q^T : lane holds q=col, kv in regs ----
        f32x16_v sa = {}, sb = {};
        __builtin_amdgcn_s_setprio(1);
#pragma unroll
        for (int ks = 0; ks < 8; ++ks) {
            const int sl = 2 * ks + hi;
            bf16x8_v af0 = *reinterpret_cast<const bf16x8_v*>(Kl + col * 256 + ((sl ^ (col & 7)) << 4));
            bf16x8_v af1 = *reinterpret_cast<const bf16x8_v*>(Kl + (32 + col) * 256 + ((sl ^ (col & 7)) << 4));
            sa = __builtin_amdgcn_mfma_f32_32x32x16_bf16(af0, bq[ks], sa, 0, 0, 0);
            sb = __builtin_amdgcn_mfma_f32_32x32x16_bf16(af1, bq[ks], sb, 0, 0, 0);
        }
        __builtin_amdgcn_s_setprio(0);

        // ---- online softmax (log2 domain), defer-max THR=8 ----
        float v = sa[0];
#pragma unroll
        for (int r = 1; r < 16; ++r) v = fmaxf(v, sa[r]);
#pragma unroll
        for (int r = 0; r < 16; ++r) v = fmaxf(v, sb[r]);
        float pmax = fmaxf(v, __shfl_xor(v, 32));
        if (!__all(pmax - m <= 8.0f)) {
            float fr = __builtin_amdgcn_exp2f(m - pmax);
            m = pmax;
            l *= fr;
#pragma unroll
            for (int r = 0; r < 16; ++r) {
                float frd = __shfl(fr, (r & 3) + 4 * hi + 8 * (r >> 2));
                of[0][r] *= frd; of[1][r] *= frd; of[2][r] *= frd; of[3][r] *= frd;
            }
        }
        float rs = 0.f;
#pragma unroll
        for (int r = 0; r < 16; ++r) { sa[r] = __builtin_amdgcn_exp2f(sa[r] - m); rs += sa[r]; }
#pragma unroll
        for (int r = 0; r < 16; ++r) { sb[r] = __builtin_amdgcn_exp2f(sb[r] - m); rs += sb[r]; }
        l += rs + __shfl_xor(rs, 32);

        // ---- pack P -> PV A-fragments (cvt_pk + permlane32_swap) ----
        bf16x8_v pa[4];
#pragma unroll
        for (int j = 0; j < 4; ++j) {
            const f32x16_v& sj = (j < 2) ? sa : sb;
            const int ro = 8 * (j & 1);
            unsigned w0, w1, w2, w3;
            asm("v_cvt_pk_bf16_f32 %0, %1, %2" : "=v"(w0) : "v"(sj[ro + 0]), "v"(sj[ro + 1]));
            asm("v_cvt_pk_bf16_f32 %0, %1, %2" : "=v"(w2) : "v"(sj[ro + 4]), "v"(sj[ro + 5]));
            asm("v_cvt_pk_bf16_f32 %0, %1, %2" : "=v"(w1) : "v"(sj[ro + 2]), "v"(sj[ro + 3]));
            asm("v_cvt_pk_bf16_f32 %0, %1, %2" : "=v"(w3) : "v"(sj[ro + 6]), "v"(sj[ro + 7]));
            asm("v_permlane32_swap_b32 %0, %1" : "+v"(w0), "+v"(w2));
            asm("v_permlane32_swap_b32 %0, %1" : "+v"(w1), "+v"(w3));
            union { unsigned u[4]; bf16x8_v h; } cvt;
            cvt.u[0] = w0; cvt.u[1] = w1; cvt.u[2] = w2; cvt.u[3] = w3;
            pa[j] = cvt.h;
        }

        // ---- O += P * V : lane holds d=col, q in regs ----
        __builtin_amdgcn_s_setprio(1);
#pragma unroll
        for (int n = 0; n < 4; ++n) {
#pragma unroll
            for (int j = 0; j < 4; ++j) {
                int row = 32 * n + col;
                bf16x8_v bv = *reinterpret_cast<const bf16x8_v*>(
                    Vl + row * 128 + (((2 * j + hi) ^ (row & 7)) << 4));
                of[n] = __builtin_amdgcn_mfma_f32_32x32x16_bf16(pa[j], bv, of[n], 0, 0, 0);
            }
        }
        __builtin_amdgcn_s_setprio(0);

        asm volatile("s_waitcnt lgkmcnt(0)" ::: "memory");
        __builtin_amdgcn_sched_barrier(0);
        __builtin_amdgcn_s_barrier();
        asm volatile("" ::: "memory");
        __builtin_amdgcn_sched_barrier(0);
    }

    // ---- epilogue: O /= l ----
    float linv = 1.0f / l;
#pragma unroll
    for (int r = 0; r < 16; ++r) {
        int qr = (r & 3) + 4 * hi + 8 * (r >> 2);
        float ld = __shfl(linv, qr);
        int qg = q0w + qr;
#pragma unroll
        for (int n = 0; n < 4; ++n)
            o_ws[base + qg * 128 + 32 * n + col] = (__bf16)(of[n][r] * ld);
    }
}

// ---------------- kernel 3: out-proj + bias + residual ----------------
__global__ __launch_bounds__(256) void k_out(const __bf16* __restrict__ o_ws,
                                             const __bf16* __restrict__ w_perm,
                                             const float* __restrict__ b_out,
                                             const float* __restrict__ x,
                                             float* __restrict__ out) {
    __shared__ __bf16 Al[64 * 136];
    __shared__ __bf16 Bl[128 * 136];
    const int tid  = threadIdx.x;
    const int lane = tid & 63, wv = tid >> 6;
    const int lr   = lane & 15, lg = lane >> 4;
    const int mt   = blockIdx.x;
    const int gp0  = mt * 64;
    const int b    = gp0 >> 10;
    const int p0   = gp0 & 1023;

    f32x4_v acc[8] = {};
    for (int kc = 0; kc < 4; ++kc) {
        __syncthreads();
#pragma unroll
        for (int it = 0; it < 4; ++it) {
            int idx = tid + it * 256;
            int rr = idx >> 4, k8 = (idx & 15) * 8;
            *reinterpret_cast<bf16x8_v*>(&Al[rr * 136 + k8]) =
                *reinterpret_cast<const bf16x8_v*>(&o_ws[(b * 4 + kc) * 131072 + (p0 + rr) * 128 + k8]);
        }
#pragma unroll
        for (int it = 0; it < 8; ++it) {
            int idx = tid + it * 256;
            int o = idx >> 4, k8 = (idx & 15) * 8;
            *reinterpret_cast<bf16x8_v*>(&Bl[o * 136 + k8]) =
                *reinterpret_cast<const bf16x8_v*>(&w_perm[kc * 16384 + o * 128 + k8]);
        }
        __syncthreads();
#pragma unroll
        for (int ks = 0; ks < 4; ++ks) {
            bf16x8_v af = *reinterpret_cast<const bf16x8_v*>(&Al[(wv * 16 + lr) * 136 + ks * 32 + lg * 8]);
#pragma unroll
            for (int ni = 0; ni < 8; ++ni) {
                bf16x8_v bf_ = *reinterpret_cast<const bf16x8_v*>(&Bl[(ni * 16 + lr) * 136 + ks * 32 + lg * 8]);
                acc[ni] = __builtin_amdgcn_mfma_f32_16x16x32_bf16(af, bf_, acc[ni], 0, 0, 0);
            }
        }
    }

    int prow = p0 + wv * 16 + lg * 4;
#pragma unroll
    for (int ni = 0; ni < 8; ++ni) {
        int o = ni * 16 + lr;
        float bias = b_out[o];
        float4 xr = *reinterpret_cast<const float4*>(&x[b * 131072 + o * 1024 + prow]);
        float4 res;
        res.x = acc[ni][0] + bias + xr.x;
        res.y = acc[ni][1] + bias + xr.y;
        res.z = acc[ni][2] + bias + xr.z;
        res.w = acc[ni][3] + bias + xr.w;
        *reinterpret_cast<float4*>(&out[b * 131072 + o * 1024 + prow]) = res;
    }
}

extern "C" void kernel_launch(void* const* d_in, const int* in_sizes, int n_in,
                              void* d_out, int out_size, void* d_ws, size_t ws_size,
                              hipStream_t stream) {
    const float* x     = (const float*)d_in[0];
    const float* w_qkv = (const float*)d_in[1];
    const float* b_qkv = (const float*)d_in[2];
    const float* w_out = (const float*)d_in[3];
    const float* b_out = (const float*)d_in[4];
    float* out = (float*)d_out;
    __bf16* ws = (__bf16*)d_ws;

    __bf16* q_ws   = ws + WS_Q;
    __bf16* k_ws   = ws + WS_K;
    __bf16* v_ws   = ws + WS_V;
    __bf16* o_ws   = ws + WS_O;
    __bf16* w_perm = ws + WS_WP;

    k_permute<<<256, 256, 0, stream>>>(w_out, w_perm);
    k_qkv<<<dim3(12, 128), 256, 0, stream>>>(x, w_qkv, b_qkv, q_ws, k_ws, v_ws);
    k_attn<<<512, 256, 0, stream>>>(q_ws, k_ws, v_ws, o_ws);
    k_out<<<256, 256, 0, stream>>>(o_ws, w_perm, b_out, x, out);
}